// Round 1
// baseline (263.517 us; speedup 1.0000x reference)
//
#include <hip/hip_runtime.h>

// Weighted BCE mean-reduction, N = 33,554,432 fp32 + int32 labels.
// History: R1/R2 ~106 us (2.4 TB/s, L1/TCP fill-path cap). R4: nontemporal
// loads bypass L1 -> kernel <= ~77 us (~3.5 TB/s read; harness 512 MiB fills
// at 78.6 us / 6.85 TB/s WRITE are the top dispatches). R5: widening MLP
// 4->8 pairs was null (257.7->257.4) => not outstanding-count-bound.
// R6 (this): theory = TCP->VGPR return path caps reads at ~3.5 TB/s; writes
// have no return path (6.8 TB/s). Route reads through global_load_lds
// (direct-to-LDS DMA, no VGPR writeback): per-wave-private double-buffered
// LDS slices, counted s_waitcnt vmcnt(2), ZERO barriers, ds_read_b128
// consume. Same thread->element mapping => bit-identical sum.

#define WBCE_BLOCK 256
#define WBCE_GRID  2048            // 256 CUs x 8 blocks/CU = 32 waves/CU (max)
#define WBCE_STRIDE (WBCE_GRID * WBCE_BLOCK)   // 524288 threads
#define WBCE_ITERS 16              // n4 / WBCE_STRIDE when N = 33554432

typedef float fx4 __attribute__((ext_vector_type(4)));
typedef int   ix4 __attribute__((ext_vector_type(4)));

__device__ __forceinline__ float wbce_elem(float x, int y, float lw0, float lw1) {
    // returns w * ln(t) with lw = w*ln2 pre-folded: lw_sel * log2(t)
    float t  = (y == 1) ? x : (1.0f - x);
    float lw = (y == 1) ? lw1 : lw0;
    return lw * __log2f(t);
}

__device__ __forceinline__ float wbce_quad(fx4 xv, ix4 yv, float lw0, float lw1) {
    float a = wbce_elem(xv.x, yv.x, lw0, lw1);
    float b = wbce_elem(xv.y, yv.y, lw0, lw1);
    float c = wbce_elem(xv.z, yv.z, lw0, lw1);
    float d = wbce_elem(xv.w, yv.w, lw0, lw1);
    return (a + b) + (c + d);
}

// Direct-to-LDS 16B load. Dest is wave-uniform base; HW scatters lane*16.
// aux=2 => NT (don't allocate in caches; this is a pure stream).
__device__ __forceinline__ void wbce_gll16(const void* g, void* l) {
    __builtin_amdgcn_global_load_lds(
        (const __attribute__((address_space(1))) void*)g,
        (__attribute__((address_space(3))) void*)l,
        16, 0, 2);
}

__global__ __launch_bounds__(WBCE_BLOCK) void weightedBCE_75582834475452_kernel(
    const fx4* __restrict__ x4,
    const ix4* __restrict__ y4,
    const float* __restrict__ weights,
    float*       __restrict__ out,
    int n4, int n, float inv_n)
{
    const float ln2 = 0.69314718055994530942f;
    const float lw0 = weights[0] * ln2;
    const float lw1 = weights[1] * ln2;

    float acc = 0.0f;  // accumulates w * ln(t); final loss = -acc
    const int tid = blockIdx.x * WBCE_BLOCK + threadIdx.x;

    // Per-wave-private staging: [wave][buf][lane]. 16 KiB/block total ->
    // LDS allows 10 blocks/CU; wave limit keeps us at 8 blocks/CU (32 waves).
    __shared__ fx4 sx[WBCE_BLOCK / 64][2][64];
    __shared__ ix4 sy[WBCE_BLOCK / 64][2][64];

    if (n4 == WBCE_ITERS * WBCE_STRIDE) {
        const int wave = threadIdx.x >> 6;
        const int lane = threadIdx.x & 63;

        // Prologue: stage iter 0 into buf 0.
        wbce_gll16(&x4[tid], &sx[wave][0][0]);
        wbce_gll16(&y4[tid], &sy[wave][0][0]);

        #pragma unroll
        for (int i = 0; i < WBCE_ITERS; ++i) {
            const int cur = i & 1;
            if (i + 1 < WBCE_ITERS) {
                // Issue next tile's DMA before consuming current one.
                wbce_gll16(&x4[tid + (i + 1) * WBCE_STRIDE], &sx[wave][cur ^ 1][0]);
                wbce_gll16(&y4[tid + (i + 1) * WBCE_STRIDE], &sy[wave][cur ^ 1][0]);
                // Wait only for iter i's 2 loads; the 2 just issued stay in flight.
                asm volatile("s_waitcnt vmcnt(2)" ::: "memory");
            } else {
                asm volatile("s_waitcnt vmcnt(0)" ::: "memory");
            }
            // Wave-private slice: no __syncthreads anywhere.
            fx4 xv = sx[wave][cur][lane];
            ix4 yv = sy[wave][cur][lane];
            acc += wbce_quad(xv, yv, lw0, lw1);
        }
    } else {
        // Generic fallback (grid-stride) — correctness for any N.
        for (int i = tid; i < n4; i += WBCE_STRIDE) {
            fx4 xv = __builtin_nontemporal_load(&x4[i]);
            ix4 yv = __builtin_nontemporal_load(&y4[i]);
            acc += wbce_quad(xv, yv, lw0, lw1);
        }
        const float* xs = (const float*)x4;
        const int*   ys = (const int*)y4;
        for (int i = n4 * 4 + tid; i < n; i += WBCE_STRIDE) {
            acc += wbce_elem(xs[i], ys[i], lw0, lw1);
        }
    }

    // wave-64 butterfly reduce
    #pragma unroll
    for (int off = 32; off > 0; off >>= 1)
        acc += __shfl_down(acc, off, 64);

    __shared__ float smem[WBCE_BLOCK / 64];
    const int lane = threadIdx.x & 63;
    const int wave = threadIdx.x >> 6;
    if (lane == 0) smem[wave] = acc;
    __syncthreads();

    if (threadIdx.x == 0) {
        float total = 0.0f;
        #pragma unroll
        for (int w = 0; w < WBCE_BLOCK / 64; ++w) total += smem[w];
        // loss = -sum(w*ln t); pre-scale by 1/N so d_out holds the mean
        atomicAdd(out, -total * inv_n);
    }
}

extern "C" void kernel_launch(void* const* d_in, const int* in_sizes, int n_in,
                              void* d_out, int out_size, void* d_ws, size_t ws_size,
                              hipStream_t stream) {
    const float* x = (const float*)d_in[0];
    const int*   y = (const int*)d_in[1];
    const float* w = (const float*)d_in[2];
    float* out = (float*)d_out;
    const int n  = in_sizes[0];
    const int n4 = n >> 2;

    // d_out is poisoned to 0xAA before every timed replay — zero it on-stream
    // (hipMemsetAsync is graph-capture safe).
    (void)hipMemsetAsync(out, 0, sizeof(float), stream);

    weightedBCE_75582834475452_kernel<<<WBCE_GRID, WBCE_BLOCK, 0, stream>>>(
        (const fx4*)x, (const ix4*)y, w, out, n4, n, 1.0f / (float)n);
}